// Round 17
// baseline (330.816 us; speedup 1.0000x reference)
//
#include <hip/hip_runtime.h>

#define BB 8192
#define DD 1024
#define HH 512
#define LL 64
#define KNN 15
#define NT 64            // 8192/128 tiles per dim
#define NTILES 2080      // NT*(NT+1)/2
#define NG1 256          // fused G1 blocks
#define NEDGE (BB * KNN)
#define NEBLK (NEDGE / 128)  // 960 edge blocks

typedef __attribute__((ext_vector_type(4))) float f32x4;
typedef __attribute__((ext_vector_type(8))) short s16x8;
typedef __attribute__((ext_vector_type(8))) unsigned short u16x8;
typedef __attribute__((ext_vector_type(4))) unsigned short u16x4;
typedef __attribute__((ext_vector_type(4))) _Float16 f16x4;

typedef s16x8 fragT;

__device__ __forceinline__ unsigned short f2bf(float f) {
  unsigned u = __float_as_uint(f);
  return (unsigned short)((u + 0x7fffu + ((u >> 16) & 1u)) >> 16);  // RNE
}

__device__ __forceinline__ void gload16(const void* g, void* l) {
  __builtin_amdgcn_global_load_lds((const __attribute__((address_space(1))) unsigned int*)g,
                                   (__attribute__((address_space(3))) unsigned int*)l, 16, 0, 0);
}

__device__ __forceinline__ float unpack_d2(unsigned u) {
  _Float16 h = __builtin_bit_cast(_Float16, (unsigned short)(u >> 16));
  return (float)h;
}

// sorted ascending top-15 insert via min/max network
__device__ __forceinline__ void ins15(unsigned (&l)[KNN], unsigned u) {
  if (u < l[KNN - 1]) {
    unsigned v = u;
#pragma unroll
    for (int p = 0; p < KNN; ++p) {
      unsigned lo = min(v, l[p]);
      unsigned hi = max(v, l[p]);
      l[p] = lo;
      v = hi;
    }
  }
}

// ---------------- prep: x->bf16+norms (blocks 0..8191) + 4 weight transposes ----------------
__global__ void k_prep(const float* __restrict__ x, unsigned short* __restrict__ xb,
                       float* __restrict__ sqx,
                       const float* __restrict__ We1, const float* __restrict__ We2,
                       const float* __restrict__ Wd1, const float* __restrict__ Wd2,
                       unsigned short* __restrict__ Wt1, unsigned short* __restrict__ Wt2,
                       unsigned short* __restrict__ Wt3, unsigned short* __restrict__ Wt4) {
  __shared__ float ps[4];
  __shared__ unsigned short T[64][65];
  int b = blockIdx.x;
  int t = threadIdx.x;
  if (b < BB) {
    f32x4 v = *(const f32x4*)(x + (size_t)b * DD + t * 4);
    u16x4 o;
    float s = 0.f;
#pragma unroll
    for (int j = 0; j < 4; ++j) {
      float f = v[j];
      s += f * f;
      o[j] = f2bf(f);
    }
    *(u16x4*)(xb + (size_t)b * DD + t * 4) = o;
#pragma unroll
    for (int off = 32; off >= 1; off >>= 1) s += __shfl_down(s, off);
    if ((t & 63) == 0) ps[t >> 6] = s;
    __syncthreads();
    if (t == 0) sqx[b] = ps[0] + ps[1] + ps[2] + ps[3];
    return;
  }
  int c = b - BB;
  const float* W;
  unsigned short* Wt;
  int Kd, N, idx;
  if (c < 128)      { W = We1; Wt = Wt1; Kd = DD; N = HH; idx = c; }
  else if (c < 136) { W = We2; Wt = Wt2; Kd = HH; N = LL; idx = c - 128; }
  else if (c < 144) { W = Wd1; Wt = Wt3; Kd = LL; N = HH; idx = c - 136; }
  else              { W = Wd2; Wt = Wt4; Kd = HH; N = DD; idx = c - 144; }
  int nx = Kd >> 6;
  int k0 = (idx % nx) * 64, n0 = (idx / nx) * 64;
  int kr = t >> 4, nc = (t & 15) * 4;
#pragma unroll
  for (int q = 0; q < 4; ++q) {
    int k = kr + q * 16;
    f32x4 v = *(const f32x4*)(W + (size_t)(k0 + k) * N + n0 + nc);
#pragma unroll
    for (int j = 0; j < 4; ++j) T[nc + j][k] = f2bf(v[j]);
  }
  __syncthreads();
#pragma unroll
  for (int q = 0; q < 2; ++q) {
    int s = t + q * 256;
    int n = s >> 3, cc = (s & 7) * 8;
    u16x8 o;
#pragma unroll
    for (int j = 0; j < 8; ++j) o[j] = T[n][cc + j];
    *(u16x8*)(Wt + (size_t)(n0 + n) * Kd + k0 + cc) = o;
  }
}

// ---------------- shared MFMA-GEMM body, 2-phase pipelined k-loop ----------------
template <int NF, int RELU, int FUSE, int STF32, int STBF>
__device__ __forceinline__ void mgemm_body(
    char* LB, int m0, int n0,
    const unsigned short* __restrict__ A, const unsigned short* __restrict__ Wt,
    const float* __restrict__ bias, unsigned short* __restrict__ Cb, float* __restrict__ Cf,
    const float* __restrict__ Xref, float* __restrict__ rec_sum, int N, int Kd) {
  unsigned short* At = (unsigned short*)LB;
  unsigned short* Bt = (unsigned short*)(LB + 16384);
  int t = threadIdx.x;
  int lane = t & 63, w = t >> 6;
  int wr = w >> 1, wc = w & 1;
  int wbase = w * 64;

  const unsigned short* pA[4];
  const unsigned short* pB[NF];
#pragma unroll
  for (int q = 0; q < 4; ++q) {
    int s = q * 256 + t;
    int r = s >> 3, g = s & 7;
    pA[q] = A + (size_t)(m0 + r) * Kd + (g ^ (r & 7)) * 8;
  }
#pragma unroll
  for (int q = 0; q < NF; ++q) {
    int s = q * 256 + t;
    int r = s >> 3, g = s & 7;
    pB[q] = Wt + (size_t)(n0 + r) * Kd + (g ^ (r & 7)) * 8;
  }

  int lrow = lane & 15;
  int klo = (lane >> 4) << 4;
  int sw = (lane & 7) << 4;

  f32x4 acc[4][NF] = {};

  int ksteps = Kd >> 6;
#pragma unroll
  for (int q = 0; q < 4; ++q) { gload16(pA[q], At + (q * 256 + wbase) * 8); pA[q] += 64; }
#pragma unroll
  for (int q = 0; q < NF; ++q) { gload16(pB[q], Bt + (q * 256 + wbase) * 8); pB[q] += 64; }

  for (int kt = 0; kt < ksteps; ++kt) {
    __syncthreads();
    fragT af[2][4], bf[2][NF];
#pragma unroll
    for (int kh = 0; kh < 2; ++kh) {
      int kbyte = ((kh << 6) | klo) ^ sw;
#pragma unroll
      for (int m = 0; m < 4; ++m)
        af[kh][m] = *(const fragT*)((const char*)At + (wr * 64 + m * 16 + lrow) * 128 + kbyte);
#pragma unroll
      for (int n = 0; n < NF; ++n)
        bf[kh][n] = *(const fragT*)((const char*)Bt + (wc * NF * 16 + n * 16 + lrow) * 128 + kbyte);
    }
    __syncthreads();
    if (kt + 1 < ksteps) {
#pragma unroll
      for (int q = 0; q < 4; ++q) { gload16(pA[q], At + (q * 256 + wbase) * 8); pA[q] += 64; }
#pragma unroll
      for (int q = 0; q < NF; ++q) { gload16(pB[q], Bt + (q * 256 + wbase) * 8); pB[q] += 64; }
    }
#pragma unroll
    for (int kh = 0; kh < 2; ++kh)
#pragma unroll
      for (int m = 0; m < 4; ++m)
#pragma unroll
        for (int n = 0; n < NF; ++n)
          acc[m][n] =
              __builtin_amdgcn_mfma_f32_16x16x32_bf16(af[kh][m], bf[kh][n], acc[m][n], 0, 0, 0);
  }

  float local = 0.f;
#pragma unroll
  for (int m = 0; m < 4; ++m) {
    int row0 = m0 + wr * 64 + m * 16 + ((lane >> 4) << 2);
#pragma unroll
    for (int n = 0; n < NF; ++n) {
      int col = n0 + wc * NF * 16 + n * 16 + lrow;
      float bv = bias[col];
      f32x4 a = acc[m][n];
#pragma unroll
      for (int j = 0; j < 4; ++j) {
        float c = a[j] + bv;
        if (RELU) c = fmaxf(c, 0.f);
        if (FUSE) {
          float xv = Xref[(size_t)(row0 + j) * N + col];
          float d = c - xv;
          local = fmaf(d, d, local);
        }
        if (STBF) Cb[(size_t)(row0 + j) * N + col] = f2bf(c);
        if (STF32) Cf[(size_t)(row0 + j) * N + col] = c;
      }
    }
  }
  if (FUSE) {
#pragma unroll
    for (int off = 32; off >= 1; off >>= 1) local += __shfl_down(local, off);
    __shared__ float rs[4];
    if ((t & 63) == 0) rs[t >> 6] = local;
    __syncthreads();
    if (t == 0) atomicAdd(rec_sum, rs[0] + rs[1] + rs[2] + rs[3]);
  }
}

// ---------------- fat kernel: G1 (first 256 blocks) + Gram/top-15 ----------------
__global__ __launch_bounds__(256, 3) void k_gram_topk(
    const unsigned short* __restrict__ xb, const float* __restrict__ sqx,
    unsigned* __restrict__ part,
    const unsigned short* __restrict__ Wt1, const float* __restrict__ be1,
    unsigned short* __restrict__ hb) {
  __shared__ __attribute__((aligned(16))) char LB[33792];

  int bid0 = blockIdx.x;
  if (bid0 < NG1) {
    mgemm_body<4, 1, 0, 0, 1>(LB, (bid0 >> 2) * 128, (bid0 & 3) * 128,
                              xb, Wt1, be1, hb, nullptr, nullptr, nullptr, HH, DD);
    return;
  }

  unsigned short* At = (unsigned short*)LB;
  unsigned short* Bt = (unsigned short*)(LB + 16384);
  char* Sf = LB;                                  // scan phase (overlays At)
  unsigned* scratch = (unsigned*)(LB + 16384);    // scan phase (overlays Bt)
  float* sqr = (float*)(LB + 32768);
  float* sqc = (float*)(LB + 33280);

  int g = bid0 - NG1;
  int k = g & 7, m = g >> 3;
  int nA = 6 + 4 * (61 - 4 * k);
  int b, mm;
  if (m < nA) { b = k; mm = m; }
  else        { b = 15 - k; mm = m - nA; }
  int ctl, j;
  if (mm < 6) {
    if (mm < 1)      { ctl = 0; j = mm; }
    else if (mm < 3) { ctl = 1; j = mm - 1; }
    else             { ctl = 2; j = mm - 3; }
  } else {
    ctl = 3 + ((mm - 6) >> 2);
    j = (mm - 6) & 3;
  }
  int rt = 4 * b + j;
  int ct = 4 * b + ctl;
  bool diag = (rt == ct);
  int r0 = rt * 128, c0 = ct * 128;

  int t = threadIdx.x;
  int lane = t & 63, w = t >> 6;
  int wr = w >> 1, wc = w & 1;
  int wbase = w * 64;

  if (t < 128) {
    sqr[t] = sqx[r0 + t];
    sqc[t] = sqx[c0 + t];
  }

  const unsigned short* pA[4];
  const unsigned short* pB[4];
#pragma unroll
  for (int q = 0; q < 4; ++q) {
    int s = q * 256 + t;
    int r = s >> 3, gg = s & 7;
    int kk = (gg ^ (r & 7)) * 8;
    pA[q] = xb + (size_t)(r0 + r) * DD + kk;
    pB[q] = xb + (size_t)(c0 + r) * DD + kk;
  }

  int lrow = lane & 15;
  int klo = (lane >> 4) << 4;
  int sw = (lane & 7) << 4;

  f32x4 acc[16] = {};

#pragma unroll
  for (int q = 0; q < 4; ++q) {
    gload16(pA[q], At + (q * 256 + wbase) * 8); pA[q] += 64;
    gload16(pB[q], Bt + (q * 256 + wbase) * 8); pB[q] += 64;
  }

  for (int kt = 0; kt < 16; ++kt) {
    __syncthreads();  // stage(kt) landed
    fragT af[2][4], bf[2][4];
#pragma unroll
    for (int kh = 0; kh < 2; ++kh) {
      int kbyte = ((kh << 6) | klo) ^ sw;
#pragma unroll
      for (int mq = 0; mq < 4; ++mq)
        af[kh][mq] = *(const fragT*)((const char*)At + (wr * 64 + mq * 16 + lrow) * 128 + kbyte);
#pragma unroll
      for (int n = 0; n < 4; ++n)
        bf[kh][n] = *(const fragT*)((const char*)Bt + (wc * 64 + n * 16 + lrow) * 128 + kbyte);
    }
    __syncthreads();  // all waves consumed LDS
    if (kt < 15) {
#pragma unroll
      for (int q = 0; q < 4; ++q) {
        gload16(pA[q], At + (q * 256 + wbase) * 8); pA[q] += 64;
        gload16(pB[q], Bt + (q * 256 + wbase) * 8); pB[q] += 64;
      }
    }
#pragma unroll
    for (int kh = 0; kh < 2; ++kh)
#pragma unroll
      for (int mq = 0; mq < 4; ++mq)
#pragma unroll
        for (int n = 0; n < 4; ++n)
          acc[mq * 4 + n] = __builtin_amdgcn_mfma_f32_16x16x32_bf16(af[kh][mq], bf[kh][n],
                                                                   acc[mq * 4 + n], 0, 0, 0);
  }

  unsigned rowlist[KNN];
#pragma unroll
  for (int p = 0; p < KNN; ++p) rowlist[p] = 0xFFFFFFFFu;

  int scanrow = t & 127, side = t >> 7;

#pragma unroll
  for (int nh = 0; nh < 2; ++nh) {
    if (wc == nh) {
#pragma unroll
      for (int mq = 0; mq < 4; ++mq) {
        int row0 = wr * 64 + mq * 16 + ((lane >> 4) << 2);
        f32x4 sq4 = *(const f32x4*)&sqr[row0];
#pragma unroll
        for (int n = 0; n < 4; ++n) {
          int colL = n * 16 + lrow;
          float sc = sqc[nh * 64 + colL];
          f32x4 a = acc[mq * 4 + n];
          f16x4 hv;
#pragma unroll
          for (int r = 0; r < 4; ++r) {
            float d2 = fmaxf(sq4[r] + sc - 2.f * a[r], 0.f);
            if (diag && (row0 + r == nh * 64 + colL)) d2 = 60000.f;
            hv[r] = (_Float16)d2;
          }
          *(f16x4*)(Sf + colL * 256 + (((row0 * 2)) ^ ((colL & 31) << 3))) = hv;
        }
      }
    }
    __syncthreads();
    // row-scan: 2 threads/row, 32 cols each; chunk-of-4 min prefilter
    {
      int cbase = side * 32;
      int jbase = c0 + nh * 64;
      for (int cc = 0; cc < 32; cc += 4) {
        unsigned u[4];
#pragma unroll
        for (int q = 0; q < 4; ++q) {
          int colL = cbase + cc + q;
          unsigned bits = *(const unsigned short*)(Sf + colL * 256 +
                                                   ((scanrow * 2) ^ ((colL & 31) << 3)));
          u[q] = (bits << 16) | (unsigned)(jbase + colL);
        }
        unsigned m4 = min(min(u[0], u[1]), min(u[2], u[3]));
        if (m4 < rowlist[KNN - 1]) {
#pragma unroll
          for (int q = 0; q < 4; ++q) ins15(rowlist, u[q]);
        }
      }
    }
    // col-scan: b64 loads of 4 consecutive rows + min prefilter
    if (!diag) {
      int c = t & 63, seg = t >> 6;
      unsigned collist[KNN];
#pragma unroll
      for (int p = 0; p < KNN; ++p) collist[p] = 0xFFFFFFFFu;
      for (int rq = 0; rq < 8; ++rq) {
        int r = seg * 32 + rq * 4;
        u16x4 v4 = *(const u16x4*)(Sf + c * 256 + ((r * 2) ^ ((c & 31) << 3)));
        unsigned u[4];
#pragma unroll
        for (int jj = 0; jj < 4; ++jj) u[jj] = ((unsigned)v4[jj] << 16) | (unsigned)(r0 + r + jj);
        unsigned m4 = min(min(u[0], u[1]), min(u[2], u[3]));
        if (m4 < collist[KNN - 1]) {
#pragma unroll
          for (int jj = 0; jj < 4; ++jj) ins15(collist, u[jj]);
        }
      }
      __syncthreads();
#pragma unroll
      for (int p = 0; p < KNN; ++p) scratch[(c * 4 + seg) * KNN + p] = collist[p];
      __syncthreads();
      if (t < 64) {
        unsigned fin[KNN];
#pragma unroll
        for (int p = 0; p < KNN; ++p) fin[p] = 0xFFFFFFFFu;
        for (int s = 0; s < 4; ++s)
#pragma unroll
          for (int p = 0; p < KNN; ++p) ins15(fin, scratch[(t * 4 + s) * KNN + p]);
        int jj = c0 + nh * 64 + t;
#pragma unroll
        for (int p = 0; p < KNN; ++p) part[((size_t)(rt * KNN + p)) * BB + jj] = fin[p];
      }
    }
    __syncthreads();
  }

  // merge the 2 per-side row lists, write slot ct
#pragma unroll
  for (int p = 0; p < KNN; ++p) scratch[(scanrow * 2 + side) * KNN + p] = rowlist[p];
  __syncthreads();
  if (t < 128) {
    unsigned fin[KNN];
#pragma unroll
    for (int p = 0; p < KNN; ++p) fin[p] = 0xFFFFFFFFu;
    for (int s = 0; s < 2; ++s)
#pragma unroll
      for (int p = 0; p < KNN; ++p) ins15(fin, scratch[(t * 2 + s) * KNN + p]);
    int i = r0 + t;
#pragma unroll
    for (int p = 0; p < KNN; ++p) part[((size_t)(ct * KNN + p)) * BB + i] = fin[p];
  }
}

// ---------------- merge / edge bodies (same logic as r16 standalone kernels) ----------------
__device__ __forceinline__ void merge1_body(int gid, const unsigned* __restrict__ part,
                                            unsigned* __restrict__ part2) {
  int s = gid >> 13, i = gid & 8191;
  unsigned l[KNN];
#pragma unroll
  for (int p = 0; p < KNN; ++p) l[p] = 0xFFFFFFFFu;
  for (int b = s * 16; b < s * 16 + 16; ++b) {
    size_t base = (size_t)(b * KNN) * BB + i;
    unsigned u = part[base];
    if (u < l[KNN - 1]) {
      ins15(l, u);
      for (int p = 1; p < KNN; ++p) {
        u = part[base + (size_t)p * BB];
        if (u >= l[KNN - 1]) break;
        ins15(l, u);
      }
    }
  }
#pragma unroll
  for (int p = 0; p < KNN; ++p) part2[((size_t)(s * KNN + p)) * BB + i] = l[p];
}

__device__ __forceinline__ void merge2_body(int i, const unsigned* __restrict__ part2,
                                            float* __restrict__ knn_d2, int* __restrict__ knn_idx,
                                            int* __restrict__ xmax_bits) {
  unsigned l[KNN];
#pragma unroll
  for (int p = 0; p < KNN; ++p) l[p] = 0xFFFFFFFFu;
  for (int q = 0; q < 4; ++q) {
    size_t base = (size_t)(q * KNN) * BB + i;
    unsigned u = part2[base];
    if (u < l[KNN - 1]) {
      ins15(l, u);
      for (int p = 1; p < KNN; ++p) {
        u = part2[base + (size_t)p * BB];
        if (u >= l[KNN - 1]) break;
        ins15(l, u);
      }
    }
  }
  float mx = 0.f;
#pragma unroll
  for (int p = 0; p < KNN; ++p) {
    unsigned u = l[p];
    float d = fmaxf(unpack_d2(u), 0.f);
    mx = fmaxf(mx, d);
    knn_d2[(size_t)i * KNN + p] = d;
    knn_idx[(size_t)i * KNN + p] = (int)(u & 0xFFFFu);
  }
  int t = threadIdx.x;
#pragma unroll
  for (int off = 32; off >= 1; off >>= 1) mx = fmaxf(mx, __shfl_down(mx, off));
  __shared__ float rm[4];
  if ((t & 63) == 0) rm[t >> 6] = mx;
  __syncthreads();
  if (t == 0) {
    float mb = fmaxf(fmaxf(rm[0], rm[1]), fmaxf(rm[2], rm[3]));
    atomicMax(xmax_bits, __float_as_int(mb));
  }
}

__device__ __forceinline__ void edge_body(int eb, const float* __restrict__ z,
                                          const int* __restrict__ knn_idx,
                                          const float* __restrict__ knn_d2,
                                          float* __restrict__ pzz, float* __restrict__ pxx,
                                          float* __restrict__ pxz, float* __restrict__ pcnt,
                                          float* __restrict__ pzm) {
  int t = threadIdx.x;
  int g = t >> 4, L = t & 15;
  int lane = t & 63;
  float szz = 0.f, sxx = 0.f, sxz = 0.f, scnt = 0.f, zm = 0.f;
#pragma unroll
  for (int pass = 0; pass < 8; ++pass) {
    int e = eb * 128 + pass * 16 + g;
    int i = e / KNN;
    int j = knn_idx[e];
    f32x4 zi = *(const f32x4*)(z + (size_t)i * LL + L * 4);
    f32x4 zj = *(const f32x4*)(z + (size_t)j * LL + L * 4);
    float v = 0.f;
#pragma unroll
    for (int d = 0; d < 4; ++d) {
      float df = zi[d] - zj[d];
      v = fmaf(df, df, v);
    }
    v += __shfl_down(v, 8);
    v += __shfl_down(v, 4);
    v += __shfl_down(v, 2);
    v += __shfl_down(v, 1);
    int cand = (L < KNN) ? knn_idx[(size_t)j * KNN + L] : -1;
    unsigned long long ball = __ballot(cand == i);
    unsigned recip = (unsigned)(ball >> (lane & 48)) & 0xFFFFu;
    if (L == 0) {
      float w = recip ? 1.f : 2.f;
      float xd2 = knn_d2[e];
      szz = fmaf(w, v, szz);
      sxx = fmaf(w, xd2, sxx);
      sxz = fmaf(w, sqrtf(v * xd2), sxz);
      scnt += w;
      zm = fmaxf(zm, v);
    }
  }
#pragma unroll
  for (int off = 32; off >= 1; off >>= 1) {
    szz += __shfl_down(szz, off);
    sxx += __shfl_down(sxx, off);
    sxz += __shfl_down(sxz, off);
    scnt += __shfl_down(scnt, off);
    zm = fmaxf(zm, __shfl_down(zm, off));
  }
  __shared__ float r[5][4];
  int w4 = t >> 6;
  if (lane == 0) {
    r[0][w4] = szz; r[1][w4] = sxx; r[2][w4] = sxz; r[3][w4] = scnt; r[4][w4] = zm;
  }
  __syncthreads();
  if (t == 0) {
    pzz[eb] = r[0][0] + r[0][1] + r[0][2] + r[0][3];
    pxx[eb] = r[1][0] + r[1][1] + r[1][2] + r[1][3];
    pxz[eb] = r[2][0] + r[2][1] + r[2][2] + r[2][3];
    pcnt[eb] = r[3][0] + r[3][1] + r[3][2] + r[3][3];
    pzm[eb] = fmaxf(fmaxf(r[4][0], r[4][1]), fmaxf(r[4][2], r[4][3]));
  }
}

// ---------------- fused tails ----------------
// tail2: G2 (64 blocks) + merge1 (128 blocks)
__global__ __launch_bounds__(256) void k_tail2(
    const unsigned short* __restrict__ hb, const unsigned short* __restrict__ Wt2,
    const float* __restrict__ be2, unsigned short* __restrict__ zb, float* __restrict__ z,
    const unsigned* __restrict__ part, unsigned* __restrict__ part2) {
  __shared__ __attribute__((aligned(16))) char LB[16384 + 8192];
  int bid = blockIdx.x;
  if (bid < 64) {
    mgemm_body<2, 0, 0, 1, 1>(LB, bid * 128, 0, hb, Wt2, be2, zb, z, nullptr, nullptr, LL, HH);
  } else {
    merge1_body((bid - 64) * 256 + threadIdx.x, part, part2);
  }
}

// tail3: G3 (256 blocks) + merge2 (32 blocks)
__global__ __launch_bounds__(256) void k_tail3(
    const unsigned short* __restrict__ zb, const unsigned short* __restrict__ Wt3,
    const float* __restrict__ bd1, unsigned short* __restrict__ h2b,
    const unsigned* __restrict__ part2, float* __restrict__ knn_d2, int* __restrict__ knn_idx,
    int* __restrict__ xmax_bits) {
  __shared__ __attribute__((aligned(16))) char LB[16384 + 16384];
  int bid = blockIdx.x;
  if (bid < 256) {
    mgemm_body<4, 1, 0, 0, 1>(LB, (bid >> 2) * 128, (bid & 3) * 128, zb, Wt3, bd1, h2b, nullptr,
                              nullptr, nullptr, HH, LL);
  } else {
    merge2_body((bid - 256) * 256 + threadIdx.x, part2, knn_d2, knn_idx, xmax_bits);
  }
}

// tail4: G4 (512 blocks) + edge (960 blocks)
__global__ __launch_bounds__(256) void k_tail4(
    const unsigned short* __restrict__ h2b, const unsigned short* __restrict__ Wt4,
    const float* __restrict__ bd2, const float* __restrict__ x, float* __restrict__ rec_sum,
    const float* __restrict__ z, const int* __restrict__ knn_idx,
    const float* __restrict__ knn_d2, float* __restrict__ pzz, float* __restrict__ pxx,
    float* __restrict__ pxz, float* __restrict__ pcnt, float* __restrict__ pzm) {
  __shared__ __attribute__((aligned(16))) char LB[16384 + 16384];
  int bid = blockIdx.x;
  if (bid < 512) {
    mgemm_body<4, 0, 1, 0, 0>(LB, (bid >> 3) * 128, (bid & 7) * 128, h2b, Wt4, bd2, nullptr,
                              nullptr, x, rec_sum, DD, HH);
  } else {
    edge_body(bid - 512, z, knn_idx, knn_d2, pzz, pxx, pxz, pcnt, pzm);
  }
}

// ---------------- final: reduce partials, assemble scalar loss ----------------
__global__ void k_final(const float* __restrict__ pzz, const float* __restrict__ pxx,
                        const float* __restrict__ pxz, const float* __restrict__ pcnt,
                        const float* __restrict__ pzm, const int* __restrict__ xmax_bits,
                        const float* __restrict__ rec_sum, float* __restrict__ out) {
  int t = threadIdx.x;
  float szz = 0.f, sxx = 0.f, sxz = 0.f, scnt = 0.f, zm = 0.f;
  for (int bb = t; bb < NEBLK; bb += 256) {
    szz += pzz[bb];
    sxx += pxx[bb];
    sxz += pxz[bb];
    scnt += pcnt[bb];
    zm = fmaxf(zm, pzm[bb]);
  }
#pragma unroll
  for (int off = 32; off >= 1; off >>= 1) {
    szz += __shfl_down(szz, off);
    sxx += __shfl_down(sxx, off);
    sxz += __shfl_down(sxz, off);
    scnt += __shfl_down(scnt, off);
    zm = fmaxf(zm, __shfl_down(zm, off));
  }
  __shared__ float r[5][4];
  int w4 = t >> 6;
  if ((t & 63) == 0) {
    r[0][w4] = szz; r[1][w4] = sxx; r[2][w4] = sxz; r[3][w4] = scnt; r[4][w4] = zm;
  }
  __syncthreads();
  if (t == 0) {
    float SZZ = r[0][0] + r[0][1] + r[0][2] + r[0][3];
    float SXX = r[1][0] + r[1][1] + r[1][2] + r[1][3];
    float SXZ = r[2][0] + r[2][1] + r[2][2] + r[2][3];
    float CNT = r[3][0] + r[3][1] + r[3][2] + r[3][3];
    float ZM = fmaxf(fmaxf(r[4][0], r[4][1]), fmaxf(r[4][2], r[4][3]));
    float xmax = __int_as_float(*xmax_bits);
    float a = 1.f / (sqrtf(ZM) + 1e-8f);
    float bq = 1.f / (sqrtf(xmax) + 1e-8f);
    float loss = (a * a * SZZ + bq * bq * SXX - 2.f * a * bq * SXZ) / CNT;
    out[0] = rec_sum[0] * (1.f / 8388608.f) + loss;
  }
}

extern "C" void kernel_launch(void* const* d_in, const int* in_sizes, int n_in,
                              void* d_out, int out_size, void* d_ws, size_t ws_size,
                              hipStream_t stream) {
  const float* x = (const float*)d_in[0];
  const float* We1 = (const float*)d_in[1];
  const float* be1 = (const float*)d_in[2];
  const float* We2 = (const float*)d_in[3];
  const float* be2 = (const float*)d_in[4];
  const float* Wd1 = (const float*)d_in[5];
  const float* bd1 = (const float*)d_in[6];
  const float* Wd2 = (const float*)d_in[7];
  const float* bd2 = (const float*)d_in[8];

  char* ws = (char*)d_ws;
  size_t off = 0;
  auto alloc = [&](size_t bytes) {
    void* p = ws + off;
    off += (bytes + 255) & ~(size_t)255;
    return p;
  };
  unsigned short* xb = (unsigned short*)alloc((size_t)BB * DD * 2);
  unsigned short* hb = (unsigned short*)alloc((size_t)BB * HH * 2);
  unsigned short* zb = (unsigned short*)alloc((size_t)BB * LL * 2);
  unsigned short* h2b = (unsigned short*)alloc((size_t)BB * HH * 2);
  float* z = (float*)alloc((size_t)BB * LL * 4);
  float* sqx = (float*)alloc((size_t)BB * 4);
  unsigned short* Wt1 = (unsigned short*)alloc((size_t)HH * DD * 2);
  unsigned short* Wt2 = (unsigned short*)alloc((size_t)LL * HH * 2);
  unsigned short* Wt3 = (unsigned short*)alloc((size_t)HH * LL * 2);
  unsigned short* Wt4 = (unsigned short*)alloc((size_t)DD * HH * 2);
  unsigned* part = (unsigned*)alloc((size_t)NT * KNN * BB * 4);   // 31.5MB
  unsigned* part2 = (unsigned*)alloc((size_t)4 * KNN * BB * 4);   // 2MB
  float* knn_d2 = (float*)alloc((size_t)BB * KNN * 4);
  int* knn_idx = (int*)alloc((size_t)BB * KNN * 4);
  float* pzz = (float*)alloc(NEBLK * 4);
  float* pxx = (float*)alloc(NEBLK * 4);
  float* pxz = (float*)alloc(NEBLK * 4);
  float* pcnt = (float*)alloc(NEBLK * 4);
  float* pzm = (float*)alloc(NEBLK * 4);
  float* scal = (float*)alloc(64);
  float* rec_sum = scal + 0;
  int* xmax_bits = (int*)(scal + 1);

  hipMemsetAsync(scal, 0, 64, stream);

  k_prep<<<BB + 272, 256, 0, stream>>>(x, xb, sqx, We1, We2, Wd1, Wd2, Wt1, Wt2, Wt3, Wt4);

  // fat kernel: G1 (256 blocks) + gram/top-15 (2080 blocks)
  k_gram_topk<<<NG1 + NTILES, 256, 0, stream>>>(xb, sqx, part, Wt1, be1, hb);

  // fused tails: {G2 || merge1}, {G3 || merge2}, {G4 || edge}
  k_tail2<<<64 + 128, 256, 0, stream>>>(hb, Wt2, be2, zb, z, part, part2);
  k_tail3<<<256 + 32, 256, 0, stream>>>(zb, Wt3, bd1, h2b, part2, knn_d2, knn_idx, xmax_bits);
  k_tail4<<<512 + NEBLK, 256, 0, stream>>>(h2b, Wt4, bd2, x, rec_sum, z, knn_idx, knn_d2,
                                           pzz, pxx, pxz, pcnt, pzm);
  k_final<<<1, 256, 0, stream>>>(pzz, pxx, pxz, pcnt, pzm, xmax_bits, rec_sum, (float*)d_out);
}

// Round 18
// 320.958 us; speedup vs baseline: 1.0307x; 1.0307x over previous
//
#include <hip/hip_runtime.h>

#define BB 8192
#define DD 1024
#define HH 512
#define LL 64
#define KNN 15
#define NT 64            // 8192/128 tiles per dim
#define NTILES 2080      // NT*(NT+1)/2
#define NG1 256          // fused G1 blocks
#define NEDGE (BB * KNN)
#define NEBLK (NEDGE / 128)  // 960 edge blocks

typedef __attribute__((ext_vector_type(4))) float f32x4;
typedef __attribute__((ext_vector_type(8))) short s16x8;
typedef __attribute__((ext_vector_type(8))) unsigned short u16x8;
typedef __attribute__((ext_vector_type(4))) unsigned short u16x4;
typedef __attribute__((ext_vector_type(4))) _Float16 f16x4;

typedef s16x8 fragT;

__device__ __forceinline__ unsigned short f2bf(float f) {
  unsigned u = __float_as_uint(f);
  return (unsigned short)((u + 0x7fffu + ((u >> 16) & 1u)) >> 16);  // RNE
}

__device__ __forceinline__ void gload16(const void* g, void* l) {
  __builtin_amdgcn_global_load_lds((const __attribute__((address_space(1))) unsigned int*)g,
                                   (__attribute__((address_space(3))) unsigned int*)l, 16, 0, 0);
}

__device__ __forceinline__ float unpack_d2(unsigned u) {
  _Float16 h = __builtin_bit_cast(_Float16, (unsigned short)(u >> 16));
  return (float)h;
}

// sorted ascending top-15 insert via min/max network
__device__ __forceinline__ void ins15(unsigned (&l)[KNN], unsigned u) {
  if (u < l[KNN - 1]) {
    unsigned v = u;
#pragma unroll
    for (int p = 0; p < KNN; ++p) {
      unsigned lo = min(v, l[p]);
      unsigned hi = max(v, l[p]);
      l[p] = lo;
      v = hi;
    }
  }
}

// ---------------- prep: x->bf16+norms (blocks 0..8191) + 4 weight transposes ----------------
__global__ void k_prep(const float* __restrict__ x, unsigned short* __restrict__ xb,
                       float* __restrict__ sqx,
                       const float* __restrict__ We1, const float* __restrict__ We2,
                       const float* __restrict__ Wd1, const float* __restrict__ Wd2,
                       unsigned short* __restrict__ Wt1, unsigned short* __restrict__ Wt2,
                       unsigned short* __restrict__ Wt3, unsigned short* __restrict__ Wt4) {
  __shared__ float ps[4];
  __shared__ unsigned short T[64][65];
  int b = blockIdx.x;
  int t = threadIdx.x;
  if (b < BB) {
    f32x4 v = *(const f32x4*)(x + (size_t)b * DD + t * 4);
    u16x4 o;
    float s = 0.f;
#pragma unroll
    for (int j = 0; j < 4; ++j) {
      float f = v[j];
      s += f * f;
      o[j] = f2bf(f);
    }
    *(u16x4*)(xb + (size_t)b * DD + t * 4) = o;
#pragma unroll
    for (int off = 32; off >= 1; off >>= 1) s += __shfl_down(s, off);
    if ((t & 63) == 0) ps[t >> 6] = s;
    __syncthreads();
    if (t == 0) sqx[b] = ps[0] + ps[1] + ps[2] + ps[3];
    return;
  }
  int c = b - BB;
  const float* W;
  unsigned short* Wt;
  int Kd, N, idx;
  if (c < 128)      { W = We1; Wt = Wt1; Kd = DD; N = HH; idx = c; }
  else if (c < 136) { W = We2; Wt = Wt2; Kd = HH; N = LL; idx = c - 128; }
  else if (c < 144) { W = Wd1; Wt = Wt3; Kd = LL; N = HH; idx = c - 136; }
  else              { W = Wd2; Wt = Wt4; Kd = HH; N = DD; idx = c - 144; }
  int nx = Kd >> 6;
  int k0 = (idx % nx) * 64, n0 = (idx / nx) * 64;
  int kr = t >> 4, nc = (t & 15) * 4;
#pragma unroll
  for (int q = 0; q < 4; ++q) {
    int k = kr + q * 16;
    f32x4 v = *(const f32x4*)(W + (size_t)(k0 + k) * N + n0 + nc);
#pragma unroll
    for (int j = 0; j < 4; ++j) T[nc + j][k] = f2bf(v[j]);
  }
  __syncthreads();
#pragma unroll
  for (int q = 0; q < 2; ++q) {
    int s = t + q * 256;
    int n = s >> 3, cc = (s & 7) * 8;
    u16x8 o;
#pragma unroll
    for (int j = 0; j < 8; ++j) o[j] = T[n][cc + j];
    *(u16x8*)(Wt + (size_t)(n0 + n) * Kd + k0 + cc) = o;
  }
}

// ---------------- shared MFMA-GEMM body, 2-phase pipelined k-loop ----------------
template <int NF, int RELU, int FUSE, int STF32, int STBF>
__device__ __forceinline__ void mgemm_body(
    char* LB, int m0, int n0,
    const unsigned short* __restrict__ A, const unsigned short* __restrict__ Wt,
    const float* __restrict__ bias, unsigned short* __restrict__ Cb, float* __restrict__ Cf,
    const float* __restrict__ Xref, float* __restrict__ rec_sum, int N, int Kd) {
  unsigned short* At = (unsigned short*)LB;
  unsigned short* Bt = (unsigned short*)(LB + 16384);
  int t = threadIdx.x;
  int lane = t & 63, w = t >> 6;
  int wr = w >> 1, wc = w & 1;
  int wbase = w * 64;

  const unsigned short* pA[4];
  const unsigned short* pB[NF];
#pragma unroll
  for (int q = 0; q < 4; ++q) {
    int s = q * 256 + t;
    int r = s >> 3, g = s & 7;
    pA[q] = A + (size_t)(m0 + r) * Kd + (g ^ (r & 7)) * 8;
  }
#pragma unroll
  for (int q = 0; q < NF; ++q) {
    int s = q * 256 + t;
    int r = s >> 3, g = s & 7;
    pB[q] = Wt + (size_t)(n0 + r) * Kd + (g ^ (r & 7)) * 8;
  }

  int lrow = lane & 15;
  int klo = (lane >> 4) << 4;
  int sw = (lane & 7) << 4;

  f32x4 acc[4][NF] = {};

  int ksteps = Kd >> 6;
  // prologue: stage step 0
#pragma unroll
  for (int q = 0; q < 4; ++q) { gload16(pA[q], At + (q * 256 + wbase) * 8); pA[q] += 64; }
#pragma unroll
  for (int q = 0; q < NF; ++q) { gload16(pB[q], Bt + (q * 256 + wbase) * 8); pB[q] += 64; }

  for (int kt = 0; kt < ksteps; ++kt) {
    __syncthreads();  // stage(kt) landed (vmcnt drained here, AFTER prev MFMAs)
    fragT af[2][4], bf[2][NF];
#pragma unroll
    for (int kh = 0; kh < 2; ++kh) {
      int kbyte = ((kh << 6) | klo) ^ sw;
#pragma unroll
      for (int m = 0; m < 4; ++m)
        af[kh][m] = *(const fragT*)((const char*)At + (wr * 64 + m * 16 + lrow) * 128 + kbyte);
#pragma unroll
      for (int n = 0; n < NF; ++n)
        bf[kh][n] = *(const fragT*)((const char*)Bt + (wc * NF * 16 + n * 16 + lrow) * 128 + kbyte);
    }
    __syncthreads();  // all waves consumed LDS into regs
    if (kt + 1 < ksteps) {
#pragma unroll
      for (int q = 0; q < 4; ++q) { gload16(pA[q], At + (q * 256 + wbase) * 8); pA[q] += 64; }
#pragma unroll
      for (int q = 0; q < NF; ++q) { gload16(pB[q], Bt + (q * 256 + wbase) * 8); pB[q] += 64; }
    }
#pragma unroll
    for (int kh = 0; kh < 2; ++kh)
#pragma unroll
      for (int m = 0; m < 4; ++m)
#pragma unroll
        for (int n = 0; n < NF; ++n)
          acc[m][n] =
              __builtin_amdgcn_mfma_f32_16x16x32_bf16(af[kh][m], bf[kh][n], acc[m][n], 0, 0, 0);
  }

  float local = 0.f;
#pragma unroll
  for (int m = 0; m < 4; ++m) {
    int row0 = m0 + wr * 64 + m * 16 + ((lane >> 4) << 2);
#pragma unroll
    for (int n = 0; n < NF; ++n) {
      int col = n0 + wc * NF * 16 + n * 16 + lrow;
      float bv = bias[col];
      f32x4 a = acc[m][n];
#pragma unroll
      for (int j = 0; j < 4; ++j) {
        float c = a[j] + bv;
        if (RELU) c = fmaxf(c, 0.f);
        if (FUSE) {
          float xv = Xref[(size_t)(row0 + j) * N + col];
          float d = c - xv;
          local = fmaf(d, d, local);
        }
        if (STBF) Cb[(size_t)(row0 + j) * N + col] = f2bf(c);
        if (STF32) Cf[(size_t)(row0 + j) * N + col] = c;
      }
    }
  }
  if (FUSE) {
#pragma unroll
    for (int off = 32; off >= 1; off >>= 1) local += __shfl_down(local, off);
    __shared__ float rs[4];
    if ((t & 63) == 0) rs[t >> 6] = local;
    __syncthreads();
    if (t == 0) atomicAdd(rec_sum, rs[0] + rs[1] + rs[2] + rs[3]);
  }
}

// ---------------- standalone MFMA GEMM ----------------
template <int NF, int RELU, int FUSE, int STF32, int STBF>
__global__ __launch_bounds__(256) void k_mgemm(
    const unsigned short* __restrict__ A, const unsigned short* __restrict__ Wt,
    const float* __restrict__ bias, unsigned short* __restrict__ Cb, float* __restrict__ Cf,
    const float* __restrict__ Xref, float* __restrict__ rec_sum, int N, int Kd) {
  __shared__ __attribute__((aligned(16))) char LB[16384 + NF * 32 * 128];
  mgemm_body<NF, RELU, FUSE, STF32, STBF>(LB, blockIdx.y * 128, blockIdx.x * (NF * 32),
                                          A, Wt, bias, Cb, Cf, Xref, rec_sum, N, Kd);
}

// ---------------- fat kernel: G1 (first 256 blocks) + Gram/top-15 ----------------
__global__ __launch_bounds__(256, 3) void k_gram_topk(
    const unsigned short* __restrict__ xb, const float* __restrict__ sqx,
    unsigned* __restrict__ part,
    const unsigned short* __restrict__ Wt1, const float* __restrict__ be1,
    unsigned short* __restrict__ hb) {
  __shared__ __attribute__((aligned(16))) char LB[33792];

  int bid0 = blockIdx.x;
  if (bid0 < NG1) {
    mgemm_body<4, 1, 0, 0, 1>(LB, (bid0 >> 2) * 128, (bid0 & 3) * 128,
                              xb, Wt1, be1, hb, nullptr, nullptr, nullptr, HH, DD);
    return;
  }

  unsigned short* At = (unsigned short*)LB;
  unsigned short* Bt = (unsigned short*)(LB + 16384);
  char* Sf = LB;                                  // scan phase (overlays At)
  unsigned* scratch = (unsigned*)(LB + 16384);    // scan phase (overlays Bt)
  float* sqr = (float*)(LB + 32768);
  float* sqc = (float*)(LB + 33280);

  int g = bid0 - NG1;
  int k = g & 7, m = g >> 3;
  int nA = 6 + 4 * (61 - 4 * k);
  int b, mm;
  if (m < nA) { b = k; mm = m; }
  else        { b = 15 - k; mm = m - nA; }
  int ctl, j;
  if (mm < 6) {
    if (mm < 1)      { ctl = 0; j = mm; }
    else if (mm < 3) { ctl = 1; j = mm - 1; }
    else             { ctl = 2; j = mm - 3; }
  } else {
    ctl = 3 + ((mm - 6) >> 2);
    j = (mm - 6) & 3;
  }
  int rt = 4 * b + j;
  int ct = 4 * b + ctl;
  bool diag = (rt == ct);
  int r0 = rt * 128, c0 = ct * 128;

  int t = threadIdx.x;
  int lane = t & 63, w = t >> 6;
  int wr = w >> 1, wc = w & 1;
  int wbase = w * 64;

  if (t < 128) {
    sqr[t] = sqx[r0 + t];
    sqc[t] = sqx[c0 + t];
  }

  const unsigned short* pA[4];
  const unsigned short* pB[4];
#pragma unroll
  for (int q = 0; q < 4; ++q) {
    int s = q * 256 + t;
    int r = s >> 3, gg = s & 7;
    int kk = (gg ^ (r & 7)) * 8;
    pA[q] = xb + (size_t)(r0 + r) * DD + kk;
    pB[q] = xb + (size_t)(c0 + r) * DD + kk;
  }

  int lrow = lane & 15;
  int klo = (lane >> 4) << 4;
  int sw = (lane & 7) << 4;

  f32x4 acc[16] = {};

  // prologue: stage step 0
#pragma unroll
  for (int q = 0; q < 4; ++q) {
    gload16(pA[q], At + (q * 256 + wbase) * 8); pA[q] += 64;
    gload16(pB[q], Bt + (q * 256 + wbase) * 8); pB[q] += 64;
  }

  for (int kt = 0; kt < 16; ++kt) {
    __syncthreads();  // stage(kt) landed
    fragT af[2][4], bf[2][4];
#pragma unroll
    for (int kh = 0; kh < 2; ++kh) {
      int kbyte = ((kh << 6) | klo) ^ sw;
#pragma unroll
      for (int mq = 0; mq < 4; ++mq)
        af[kh][mq] = *(const fragT*)((const char*)At + (wr * 64 + mq * 16 + lrow) * 128 + kbyte);
#pragma unroll
      for (int n = 0; n < 4; ++n)
        bf[kh][n] = *(const fragT*)((const char*)Bt + (wc * 64 + n * 16 + lrow) * 128 + kbyte);
    }
    __syncthreads();  // all waves consumed LDS
    if (kt < 15) {
#pragma unroll
      for (int q = 0; q < 4; ++q) {
        gload16(pA[q], At + (q * 256 + wbase) * 8); pA[q] += 64;
        gload16(pB[q], Bt + (q * 256 + wbase) * 8); pB[q] += 64;
      }
    }
#pragma unroll
    for (int kh = 0; kh < 2; ++kh)
#pragma unroll
      for (int mq = 0; mq < 4; ++mq)
#pragma unroll
        for (int n = 0; n < 4; ++n)
          acc[mq * 4 + n] = __builtin_amdgcn_mfma_f32_16x16x32_bf16(af[kh][mq], bf[kh][n],
                                                                   acc[mq * 4 + n], 0, 0, 0);
  }

  unsigned rowlist[KNN];
#pragma unroll
  for (int p = 0; p < KNN; ++p) rowlist[p] = 0xFFFFFFFFu;

  int scanrow = t & 127, side = t >> 7;

#pragma unroll
  for (int nh = 0; nh < 2; ++nh) {
    // write d2 half-tile to swizzled f16 Sf (overlays A-stage)
    if (wc == nh) {
#pragma unroll
      for (int mq = 0; mq < 4; ++mq) {
        int row0 = wr * 64 + mq * 16 + ((lane >> 4) << 2);
        f32x4 sq4 = *(const f32x4*)&sqr[row0];
#pragma unroll
        for (int n = 0; n < 4; ++n) {
          int colL = n * 16 + lrow;
          float sc = sqc[nh * 64 + colL];
          f32x4 a = acc[mq * 4 + n];
          f16x4 hv;
#pragma unroll
          for (int r = 0; r < 4; ++r) {
            float d2 = fmaxf(sq4[r] + sc - 2.f * a[r], 0.f);
            if (diag && (row0 + r == nh * 64 + colL)) d2 = 60000.f;
            hv[r] = (_Float16)d2;
          }
          *(f16x4*)(Sf + colL * 256 + (((row0 * 2)) ^ ((colL & 31) << 3))) = hv;
        }
      }
    }
    __syncthreads();
    // row-scan: 2 threads/row, 32 cols each; chunk-of-4 min prefilter
    {
      int cbase = side * 32;
      int jbase = c0 + nh * 64;
      for (int cc = 0; cc < 32; cc += 4) {
        unsigned u[4];
#pragma unroll
        for (int q = 0; q < 4; ++q) {
          int colL = cbase + cc + q;
          unsigned bits = *(const unsigned short*)(Sf + colL * 256 +
                                                   ((scanrow * 2) ^ ((colL & 31) << 3)));
          u[q] = (bits << 16) | (unsigned)(jbase + colL);
        }
        unsigned m4 = min(min(u[0], u[1]), min(u[2], u[3]));
        if (m4 < rowlist[KNN - 1]) {
#pragma unroll
          for (int q = 0; q < 4; ++q) ins15(rowlist, u[q]);
        }
      }
    }
    // col-scan: b64 loads of 4 consecutive rows + min prefilter
    if (!diag) {
      int c = t & 63, seg = t >> 6;
      unsigned collist[KNN];
#pragma unroll
      for (int p = 0; p < KNN; ++p) collist[p] = 0xFFFFFFFFu;
      for (int rq = 0; rq < 8; ++rq) {
        int r = seg * 32 + rq * 4;
        u16x4 v4 = *(const u16x4*)(Sf + c * 256 + ((r * 2) ^ ((c & 31) << 3)));
        unsigned u[4];
#pragma unroll
        for (int jj = 0; jj < 4; ++jj) u[jj] = ((unsigned)v4[jj] << 16) | (unsigned)(r0 + r + jj);
        unsigned m4 = min(min(u[0], u[1]), min(u[2], u[3]));
        if (m4 < collist[KNN - 1]) {
#pragma unroll
          for (int jj = 0; jj < 4; ++jj) ins15(collist, u[jj]);
        }
      }
      __syncthreads();
#pragma unroll
      for (int p = 0; p < KNN; ++p) scratch[(c * 4 + seg) * KNN + p] = collist[p];
      __syncthreads();
      if (t < 64) {
        unsigned fin[KNN];
#pragma unroll
        for (int p = 0; p < KNN; ++p) fin[p] = 0xFFFFFFFFu;
        for (int s = 0; s < 4; ++s)
#pragma unroll
          for (int p = 0; p < KNN; ++p) ins15(fin, scratch[(t * 4 + s) * KNN + p]);
        int jj = c0 + nh * 64 + t;
#pragma unroll
        for (int p = 0; p < KNN; ++p) part[((size_t)(rt * KNN + p)) * BB + jj] = fin[p];
      }
    }
    __syncthreads();
  }

  // merge the 2 per-side row lists, write slot ct
#pragma unroll
  for (int p = 0; p < KNN; ++p) scratch[(scanrow * 2 + side) * KNN + p] = rowlist[p];
  __syncthreads();
  if (t < 128) {
    unsigned fin[KNN];
#pragma unroll
    for (int p = 0; p < KNN; ++p) fin[p] = 0xFFFFFFFFu;
    for (int s = 0; s < 2; ++s)
#pragma unroll
      for (int p = 0; p < KNN; ++p) ins15(fin, scratch[(t * 2 + s) * KNN + p]);
    int i = r0 + t;
#pragma unroll
    for (int p = 0; p < KNN; ++p) part[((size_t)(ct * KNN + p)) * BB + i] = fin[p];
  }
}

// ---------------- merge stage 1: 64 slots -> 4, early-exit on sorted slots ----------------
__global__ void k_merge1(const unsigned* __restrict__ part, unsigned* __restrict__ part2) {
  int gid = blockIdx.x * 256 + threadIdx.x;  // 32768
  int s = gid >> 13, i = gid & 8191;
  unsigned l[KNN];
#pragma unroll
  for (int p = 0; p < KNN; ++p) l[p] = 0xFFFFFFFFu;
  for (int b = s * 16; b < s * 16 + 16; ++b) {
    size_t base = (size_t)(b * KNN) * BB + i;
    unsigned u = part[base];
    if (u < l[KNN - 1]) {
      ins15(l, u);
      for (int p = 1; p < KNN; ++p) {
        u = part[base + (size_t)p * BB];
        if (u >= l[KNN - 1]) break;
        ins15(l, u);
      }
    }
  }
#pragma unroll
  for (int p = 0; p < KNN; ++p) part2[((size_t)(s * KNN + p)) * BB + i] = l[p];
}

// ---------------- merge stage 2: final top-15 + xmax ----------------
__global__ void k_merge2(const unsigned* __restrict__ part2, float* __restrict__ knn_d2,
                         int* __restrict__ knn_idx, int* __restrict__ xmax_bits) {
  int i = blockIdx.x * 256 + threadIdx.x;
  unsigned l[KNN];
#pragma unroll
  for (int p = 0; p < KNN; ++p) l[p] = 0xFFFFFFFFu;
  for (int q = 0; q < 4; ++q) {
    size_t base = (size_t)(q * KNN) * BB + i;
    unsigned u = part2[base];
    if (u < l[KNN - 1]) {
      ins15(l, u);
      for (int p = 1; p < KNN; ++p) {
        u = part2[base + (size_t)p * BB];
        if (u >= l[KNN - 1]) break;
        ins15(l, u);
      }
    }
  }
  float mx = 0.f;
#pragma unroll
  for (int p = 0; p < KNN; ++p) {
    unsigned u = l[p];
    float d = fmaxf(unpack_d2(u), 0.f);
    mx = fmaxf(mx, d);
    knn_d2[(size_t)i * KNN + p] = d;
    knn_idx[(size_t)i * KNN + p] = (int)(u & 0xFFFFu);
  }
  int t = threadIdx.x;
#pragma unroll
  for (int off = 32; off >= 1; off >>= 1) mx = fmaxf(mx, __shfl_down(mx, off));
  __shared__ float rm[4];
  if ((t & 63) == 0) rm[t >> 6] = mx;
  __syncthreads();
  if (t == 0) {
    float mb = fmaxf(fmaxf(rm[0], rm[1]), fmaxf(rm[2], rm[3]));
    atomicMax(xmax_bits, __float_as_int(mb));
  }
}

// ---------------- fused edge kernel: zd2 + reciprocity + partial sums ----------------
__global__ void k_edge(const float* __restrict__ z, const int* __restrict__ knn_idx,
                       const float* __restrict__ knn_d2, float* __restrict__ pzz,
                       float* __restrict__ pxx, float* __restrict__ pxz,
                       float* __restrict__ pcnt, float* __restrict__ pzm) {
  int t = threadIdx.x;
  int g = t >> 4, L = t & 15;
  int lane = t & 63;
  float szz = 0.f, sxx = 0.f, sxz = 0.f, scnt = 0.f, zm = 0.f;
#pragma unroll
  for (int pass = 0; pass < 8; ++pass) {
    int e = blockIdx.x * 128 + pass * 16 + g;
    int i = e / KNN;
    int j = knn_idx[e];
    f32x4 zi = *(const f32x4*)(z + (size_t)i * LL + L * 4);
    f32x4 zj = *(const f32x4*)(z + (size_t)j * LL + L * 4);
    float v = 0.f;
#pragma unroll
    for (int d = 0; d < 4; ++d) {
      float df = zi[d] - zj[d];
      v = fmaf(df, df, v);
    }
    v += __shfl_down(v, 8);
    v += __shfl_down(v, 4);
    v += __shfl_down(v, 2);
    v += __shfl_down(v, 1);
    int cand = (L < KNN) ? knn_idx[(size_t)j * KNN + L] : -1;
    unsigned long long ball = __ballot(cand == i);
    unsigned recip = (unsigned)(ball >> (lane & 48)) & 0xFFFFu;
    if (L == 0) {
      float w = recip ? 1.f : 2.f;
      float xd2 = knn_d2[e];
      szz = fmaf(w, v, szz);
      sxx = fmaf(w, xd2, sxx);
      sxz = fmaf(w, sqrtf(v * xd2), sxz);
      scnt += w;
      zm = fmaxf(zm, v);
    }
  }
#pragma unroll
  for (int off = 32; off >= 1; off >>= 1) {
    szz += __shfl_down(szz, off);
    sxx += __shfl_down(sxx, off);
    sxz += __shfl_down(sxz, off);
    scnt += __shfl_down(scnt, off);
    zm = fmaxf(zm, __shfl_down(zm, off));
  }
  __shared__ float r[5][4];
  int w4 = t >> 6;
  if (lane == 0) {
    r[0][w4] = szz; r[1][w4] = sxx; r[2][w4] = sxz; r[3][w4] = scnt; r[4][w4] = zm;
  }
  __syncthreads();
  if (t == 0) {
    pzz[blockIdx.x] = r[0][0] + r[0][1] + r[0][2] + r[0][3];
    pxx[blockIdx.x] = r[1][0] + r[1][1] + r[1][2] + r[1][3];
    pxz[blockIdx.x] = r[2][0] + r[2][1] + r[2][2] + r[2][3];
    pcnt[blockIdx.x] = r[3][0] + r[3][1] + r[3][2] + r[3][3];
    pzm[blockIdx.x] = fmaxf(fmaxf(r[4][0], r[4][1]), fmaxf(r[4][2], r[4][3]));
  }
}

// ---------------- final: reduce partials, assemble scalar loss ----------------
__global__ void k_final(const float* __restrict__ pzz, const float* __restrict__ pxx,
                        const float* __restrict__ pxz, const float* __restrict__ pcnt,
                        const float* __restrict__ pzm, const int* __restrict__ xmax_bits,
                        const float* __restrict__ rec_sum, float* __restrict__ out) {
  int t = threadIdx.x;
  float szz = 0.f, sxx = 0.f, sxz = 0.f, scnt = 0.f, zm = 0.f;
  for (int bb = t; bb < NEBLK; bb += 256) {
    szz += pzz[bb];
    sxx += pxx[bb];
    sxz += pxz[bb];
    scnt += pcnt[bb];
    zm = fmaxf(zm, pzm[bb]);
  }
#pragma unroll
  for (int off = 32; off >= 1; off >>= 1) {
    szz += __shfl_down(szz, off);
    sxx += __shfl_down(sxx, off);
    sxz += __shfl_down(sxz, off);
    scnt += __shfl_down(scnt, off);
    zm = fmaxf(zm, __shfl_down(zm, off));
  }
  __shared__ float r[5][4];
  int w4 = t >> 6;
  if ((t & 63) == 0) {
    r[0][w4] = szz; r[1][w4] = sxx; r[2][w4] = sxz; r[3][w4] = scnt; r[4][w4] = zm;
  }
  __syncthreads();
  if (t == 0) {
    float SZZ = r[0][0] + r[0][1] + r[0][2] + r[0][3];
    float SXX = r[1][0] + r[1][1] + r[1][2] + r[1][3];
    float SXZ = r[2][0] + r[2][1] + r[2][2] + r[2][3];
    float CNT = r[3][0] + r[3][1] + r[3][2] + r[3][3];
    float ZM = fmaxf(fmaxf(r[4][0], r[4][1]), fmaxf(r[4][2], r[4][3]));
    float xmax = __int_as_float(*xmax_bits);
    float a = 1.f / (sqrtf(ZM) + 1e-8f);
    float bq = 1.f / (sqrtf(xmax) + 1e-8f);
    float loss = (a * a * SZZ + bq * bq * SXX - 2.f * a * bq * SXZ) / CNT;
    out[0] = rec_sum[0] * (1.f / 8388608.f) + loss;
  }
}

extern "C" void kernel_launch(void* const* d_in, const int* in_sizes, int n_in,
                              void* d_out, int out_size, void* d_ws, size_t ws_size,
                              hipStream_t stream) {
  const float* x = (const float*)d_in[0];
  const float* We1 = (const float*)d_in[1];
  const float* be1 = (const float*)d_in[2];
  const float* We2 = (const float*)d_in[3];
  const float* be2 = (const float*)d_in[4];
  const float* Wd1 = (const float*)d_in[5];
  const float* bd1 = (const float*)d_in[6];
  const float* Wd2 = (const float*)d_in[7];
  const float* bd2 = (const float*)d_in[8];

  char* ws = (char*)d_ws;
  size_t off = 0;
  auto alloc = [&](size_t bytes) {
    void* p = ws + off;
    off += (bytes + 255) & ~(size_t)255;
    return p;
  };
  unsigned short* xb = (unsigned short*)alloc((size_t)BB * DD * 2);
  unsigned short* hb = (unsigned short*)alloc((size_t)BB * HH * 2);
  unsigned short* zb = (unsigned short*)alloc((size_t)BB * LL * 2);
  unsigned short* h2b = (unsigned short*)alloc((size_t)BB * HH * 2);
  float* z = (float*)alloc((size_t)BB * LL * 4);
  float* sqx = (float*)alloc((size_t)BB * 4);
  unsigned short* Wt1 = (unsigned short*)alloc((size_t)HH * DD * 2);
  unsigned short* Wt2 = (unsigned short*)alloc((size_t)LL * HH * 2);
  unsigned short* Wt3 = (unsigned short*)alloc((size_t)HH * LL * 2);
  unsigned short* Wt4 = (unsigned short*)alloc((size_t)DD * HH * 2);
  unsigned* part = (unsigned*)alloc((size_t)NT * KNN * BB * 4);   // 31.5MB
  unsigned* part2 = (unsigned*)alloc((size_t)4 * KNN * BB * 4);   // 2MB
  float* knn_d2 = (float*)alloc((size_t)BB * KNN * 4);
  int* knn_idx = (int*)alloc((size_t)BB * KNN * 4);
  float* pzz = (float*)alloc(NEBLK * 4);
  float* pxx = (float*)alloc(NEBLK * 4);
  float* pxz = (float*)alloc(NEBLK * 4);
  float* pcnt = (float*)alloc(NEBLK * 4);
  float* pzm = (float*)alloc(NEBLK * 4);
  float* scal = (float*)alloc(64);
  float* rec_sum = scal + 0;
  int* xmax_bits = (int*)(scal + 1);

  hipMemsetAsync(scal, 0, 64, stream);

  k_prep<<<BB + 272, 256, 0, stream>>>(x, xb, sqx, We1, We2, Wd1, Wd2, Wt1, Wt2, Wt3, Wt4);

  // fat kernel: G1 (256 blocks) + gram/top-15 (2080 blocks)
  k_gram_topk<<<NG1 + NTILES, 256, 0, stream>>>(xb, sqx, part, Wt1, be1, hb);

  k_mgemm<2, 0, 0, 1, 1><<<dim3(LL / 64, BB / 128), 256, 0, stream>>>(
      hb, Wt2, be2, zb, z, nullptr, nullptr, LL, HH);
  k_mgemm<4, 1, 0, 0, 1><<<dim3(HH / 128, BB / 128), 256, 0, stream>>>(
      zb, Wt3, bd1, h2b, nullptr, nullptr, nullptr, HH, LL);
  k_mgemm<4, 0, 1, 0, 0><<<dim3(DD / 128, BB / 128), 256, 0, stream>>>(
      h2b, Wt4, bd2, nullptr, nullptr, x, rec_sum, DD, HH);

  k_merge1<<<128, 256, 0, stream>>>(part, part2);
  k_merge2<<<BB / 256, 256, 0, stream>>>(part2, knn_d2, knn_idx, xmax_bits);
  k_edge<<<NEBLK, 256, 0, stream>>>(z, knn_idx, knn_d2, pzz, pxx, pxz, pcnt, pzm);
  k_final<<<1, 256, 0, stream>>>(pzz, pxx, pxz, pcnt, pzm, xmax_bits, rec_sum, (float*)d_out);
}